// Round 16
// baseline (242.104 us; speedup 1.0000x reference)
//
#include <hip/hip_runtime.h>
#include <cstdint>
#include <cstddef>

#define N_NODES 4096
#define F_INF   3000
#define FPAD    3008
#define NPAD    3072
#define HIDC    256
#define NEDGE   65536
#define POOLH   128
#define GCOLS   576   // 256 (branch1) + 256 (branchA) + dnA + dnB + pad

typedef unsigned short u16;
typedef __attribute__((ext_vector_type(8))) short bf16x8;
typedef __attribute__((ext_vector_type(8))) unsigned short us8;
typedef __attribute__((ext_vector_type(4))) unsigned int u32x4;
typedef __attribute__((ext_vector_type(4))) float f32x4;

__device__ inline float lrelu(float x){ return x > 0.f ? x : 0.2f*x; }
__device__ inline u16 f2b(float f){
  uint32_t x = __builtin_bit_cast(uint32_t, f);
  uint32_t r = (x + 0x7fffu + ((x >> 16) & 1u)) >> 16;
  return (u16)r;
}
__device__ inline float b2f(u16 u){
  uint32_t x = ((uint32_t)u) << 16;
  return __builtin_bit_cast(float, x);
}
// packed f32x2 -> bf16x2 (RTNE), one instruction
__device__ __forceinline__ uint32_t cvt2(float lo, float hi){
  uint32_t r;
  asm("v_cvt_pk_bf16_f32 %0, %1, %2" : "=v"(r) : "v"(lo), "v"(hi));
  return r;
}
__device__ __forceinline__ void lds16(const void* g, void* l){
  __builtin_amdgcn_global_load_lds((const __attribute__((address_space(1))) void*)g,
                                   (__attribute__((address_space(3))) void*)l, 16, 0, 0);
}

// ---------------- CSR build ----------------
__global__ void k_deg(const int* __restrict__ dst, int* __restrict__ deg){
  int e = blockIdx.x*256 + threadIdx.x;
  if (e < NEDGE) atomicAdd(&deg[dst[e]], 1);
}

__global__ void k_scan(const int* __restrict__ deg, int* __restrict__ off){
  __shared__ int sm[1024];
  int tid = threadIdx.x;
  int v0=deg[tid*4], v1=deg[tid*4+1], v2=deg[tid*4+2], v3=deg[tid*4+3];
  int s = v0+v1+v2+v3;
  sm[tid]=s; __syncthreads();
  for (int d=1; d<1024; d<<=1){
    int t = (tid>=d)? sm[tid-d] : 0;
    __syncthreads();
    sm[tid] += t;
    __syncthreads();
  }
  int run = sm[tid]-s;
  off[tid*4+0]=run; run+=v0;
  off[tid*4+1]=run; run+=v1;
  off[tid*4+2]=run; run+=v2;
  off[tid*4+3]=run; run+=v3;
  if (tid==1023) off[N_NODES]=run;
}

__global__ void k_fill(const int* __restrict__ ei, const float* __restrict__ ew,
                       const int* __restrict__ off, int* __restrict__ cursor,
                       int* __restrict__ csr_src, float* __restrict__ csr_w){
  int e = blockIdx.x*256+threadIdx.x;
  if (e >= NEDGE) return;
  int d = ei[NEDGE + e];
  int slot = off[d] + atomicAdd(&cursor[d],1);
  csr_src[slot] = ei[e];
  csr_w[slot] = ew[e];
}

// ---------------- conversions ----------------
__global__ void k_cvt(const float* __restrict__ in, u16* __restrict__ out,
                      int R, int Cin, int Cout){
  size_t i = ((size_t)blockIdx.x*256 + threadIdx.x)*4;
  if (i >= (size_t)R*Cout) return;
  int r = (int)(i / Cout), c = (int)(i % Cout);
  ushort4 o;
  if (c + 3 < Cin){
    float4 v = *(const float4*)(in + (size_t)r*Cin + c);
    o.x=f2b(v.x); o.y=f2b(v.y); o.z=f2b(v.z); o.w=f2b(v.w);
  } else {
    float vs[4];
    #pragma unroll
    for (int j=0;j<4;j++) vs[j] = (c+j<Cin)? in[(size_t)r*Cin+c+j] : 0.f;
    o.x=f2b(vs[0]); o.y=f2b(vs[1]); o.z=f2b(vs[2]); o.w=f2b(vs[3]);
  }
  *(ushort4*)(out+i) = o;
}

// out[c][r] = in[r][c] * (scale?scale[r]:1), bf16, zero-pad outside [R][C].
__global__ void k_trcvt(const float* __restrict__ in, u16* __restrict__ out,
                        int R, int C, int OCols, const float* __restrict__ scale){
  __shared__ float t[32][33];
  int c0 = blockIdx.x*32, r0 = blockIdx.y*32;
  int tx = threadIdx.x & 31, ty = threadIdx.x >> 5;
  #pragma unroll
  for (int i=0;i<4;i++){
    int r = r0 + ty + i*8, c = c0 + tx;
    float v = (r<R && c<C) ? in[(size_t)r*C + c] : 0.f;
    if (scale && r<R) v *= scale[r];
    t[ty+i*8][tx] = v;
  }
  __syncthreads();
  #pragma unroll
  for (int i=0;i<4;i++){
    int c = c0 + ty + i*8, r = r0 + tx;
    out[(size_t)c*OCols + r] = f2b(t[tx][ty+i*8]);
  }
}

// ------- MFMA GEMM: gload_lds + counted-vmcnt 2-deep pipeline (T3/T4) -------
// C[M,N] = A[M,K] @ B^T. B [N][ldb] bf16, zero for k in [Ksrc, K). K mult 64.
// BK=64 (conflict-free swizzle: A chunk c^(row&15), B c^(row&7)).
// A chunks with gk+4 > Ksrc clamp to row start (garbage x zero-B = 0), keeping
// the per-stage load count uniform. A staged raw f32/i32 (ATYPE 0/1) via
// global_load_lds w/ XOR-source-swizzle + linear dest; bf16-cvt at read.
// CT: 0 = f32 out (+bias), 1 = bf16 out. grid (M/BM, N/BN, SPLITK).
template<int ATYPE, int BM, int BN, int NWM, int NWN, int CT>
__global__ __launch_bounds__(NWM*NWN*64) void k_mg(
    const void* __restrict__ A0v, const void* __restrict__ A1v, int srow,
    const u16* __restrict__ B, void* __restrict__ Cv,
    const float* __restrict__ bias,
    int M, int nmax, int K, int Ksrc,
    int lda, int ldb, int ldc, int kcount){
  constexpr int THREADS = NWM*NWN*64;
  constexpr int WM = BM/NWM, WN = BN/NWN, MR = WM/16, NR = WN/16;
  constexpr int APT = (BM*16)/THREADS, BPT = (BN*8)/THREADS;
  constexpr int LPT = APT + BPT;
  constexpr int ABYTES = BM*64*4, BBYTES = BN*64*2;
  __shared__ __align__(16) char L[2*ABYTES + 2*BBYTES];
  const int tid = threadIdx.x;
  const int bm = blockIdx.x*BM, bn = blockIdx.y*BN;
  const int lane = tid & 63, w = tid >> 6;
  const int wr = w / NWN, wc = w % NWN;
  f32x4 acc[MR][NR] = {};

  const int kbeg = blockIdx.z * kcount;
  const int kend = min(K, kbeg + kcount);
  const int nsteps = (kend - kbeg) >> 6;

  auto stage = [&](int kk, int half){
    char* bufA = L + half*ABYTES;
    #pragma unroll
    for (int p=0;p<APT;p++){
      int s = p*THREADS + tid, row = s>>4, c = s&15, cg = c ^ (row&15);
      int gk = kk + cg*4;
      if (gk + 4 > Ksrc) gk = 0;           // clamp: garbage * zero-B = 0
      int grow = bm + row;
      const char* Ap = (grow < srow)
          ? (const char*)A0v + ((size_t)grow*lda + gk)*4
          : (const char*)A1v + ((size_t)(grow-srow)*lda + gk)*4;
      lds16(Ap, bufA + (size_t)s*16);
    }
    char* bufB = L + 2*ABYTES + half*BBYTES;
    #pragma unroll
    for (int p=0;p<BPT;p++){
      int s = p*THREADS + tid, row = s>>3, c = s&7, cg = c ^ (row&7);
      lds16(B + (size_t)(bn+row)*ldb + kk + cg*8, bufB + (size_t)s*16);
    }
  };

  auto compute = [&](int half){
    char* bufA = L + half*ABYTES;
    char* bufB = L + 2*ABYTES + half*BBYTES;
    #pragma unroll
    for (int ks=0; ks<2; ks++){
      bf16x8 af[MR], bfv[NR];
      #pragma unroll
      for (int m=0;m<MR;m++){
        int row = wr*WM + m*16 + (lane&15);
        int g = ks*8 + (lane>>4)*2;
        int xa = row & 15;
        f32x4 a0 = *(const f32x4*)(bufA + row*256 + (((g  )^xa)<<4));
        f32x4 a1 = *(const f32x4*)(bufA + row*256 + (((g+1)^xa)<<4));
        u32x4 o;
        if (ATYPE==0){
          o[0]=cvt2(a0[0],a0[1]); o[1]=cvt2(a0[2],a0[3]);
          o[2]=cvt2(a1[0],a1[1]); o[3]=cvt2(a1[2],a1[3]);
        } else {
          u32x4 ia = __builtin_bit_cast(u32x4, a0);
          u32x4 ib = __builtin_bit_cast(u32x4, a1);
          o[0] = ia[0]*0x3F80u + ia[1]*0x3F800000u;
          o[1] = ia[2]*0x3F80u + ia[3]*0x3F800000u;
          o[2] = ib[0]*0x3F80u + ib[1]*0x3F800000u;
          o[3] = ib[2]*0x3F80u + ib[3]*0x3F800000u;
        }
        af[m] = __builtin_bit_cast(bf16x8, o);
      }
      #pragma unroll
      for (int n=0;n<NR;n++){
        int row = wc*WN + n*16 + (lane&15);
        int g = ks*4 + (lane>>4);
        bfv[n] = *(const bf16x8*)(bufB + row*128 + ((g ^ (row&7))<<4));
      }
      #pragma unroll
      for (int m=0;m<MR;m++)
        #pragma unroll
        for (int n=0;n<NR;n++)
          acc[m][n] = __builtin_amdgcn_mfma_f32_16x16x32_bf16(af[m], bfv[n], acc[m][n], 0,0,0);
    }
  };

  // prologue: 2 tiles in flight
  stage(kbeg, 0);
  if (nsteps > 1) stage(kbeg + 64, 1);

  for (int t=0; t<nsteps; ++t){
    if (t+1 < nsteps){
      if constexpr (LPT == 3)       asm volatile("s_waitcnt vmcnt(3)" ::: "memory");
      else if constexpr (LPT == 4)  asm volatile("s_waitcnt vmcnt(4)" ::: "memory");
      else if constexpr (LPT == 5)  asm volatile("s_waitcnt vmcnt(5)" ::: "memory");
      else if constexpr (LPT == 6)  asm volatile("s_waitcnt vmcnt(6)" ::: "memory");
      else if constexpr (LPT == 7)  asm volatile("s_waitcnt vmcnt(7)" ::: "memory");
      else if constexpr (LPT == 8)  asm volatile("s_waitcnt vmcnt(8)" ::: "memory");
      else if constexpr (LPT == 10) asm volatile("s_waitcnt vmcnt(10)" ::: "memory");
      else                          asm volatile("s_waitcnt vmcnt(0)" ::: "memory");
    } else {
      asm volatile("s_waitcnt vmcnt(0)" ::: "memory");
    }
    __builtin_amdgcn_s_barrier();
    __builtin_amdgcn_sched_barrier(0);     // pin ds_reads below the wait
    compute(t & 1);
    __builtin_amdgcn_s_barrier();          // all waves done reading buf(t&1)
    if (t+2 < nsteps) stage(kbeg + (t+2)*64, t & 1);
  }

  const size_t slab = (size_t)blockIdx.z * (size_t)M * ldc;
  const int rbase = bm + wr*WM + ((lane>>4)<<2);
  const int cbase = bn + wc*WN + (lane&15);
  if constexpr (CT == 1){
    u16* C = (u16*)Cv + slab;
    #pragma unroll
    for (int n=0;n<NR;n++){
      int gcol = cbase + n*16;
      if (gcol >= nmax) continue;
      #pragma unroll
      for (int m=0;m<MR;m++)
        #pragma unroll
        for (int j=0;j<4;j++)
          C[(size_t)(rbase + m*16 + j)*ldc + gcol] = f2b(acc[m][n][j]);
    }
  } else {
    float* C = (float*)Cv + slab;
    #pragma unroll
    for (int n=0;n<NR;n++){
      int gcol = cbase + n*16;
      if (gcol >= nmax) continue;
      float bv = bias ? bias[gcol] : 0.f;
      #pragma unroll
      for (int m=0;m<MR;m++)
        #pragma unroll
        for (int j=0;j<4;j++)
          C[(size_t)(rbase + m*16 + j)*ldc + gcol] = acc[m][n][j] + bv;
    }
  }
}

// ------- proj slab-reduce (4 bf16 slabs) fused with GAT1 scores -------
__global__ void k_hred(const u16* __restrict__ S, float* __restrict__ h,
                       const float* __restrict__ a_src, const float* __restrict__ a_dst,
                       float* __restrict__ ss, float* __restrict__ sd){
  const size_t SLP = (size_t)2*N_NODES*HIDC;
  int n = blockIdx.x, c = threadIdx.x;
  size_t i = (size_t)n*HIDC + c;
  float v = b2f(S[i]) + b2f(S[i+SLP]) + b2f(S[i+2*SLP]) + b2f(S[i+3*SLP]);
  h[i] = v;
  float vs = v*a_src[c], vd = v*a_dst[c];
  #pragma unroll
  for (int o=32;o>0;o>>=1){ vs += __shfl_down(vs,o); vd += __shfl_down(vd,o); }
  if ((c&63)==0){ int hh=c>>6; ss[n*4+hh]=vs; sd[n*4+hh]=vd; }
}

// ---------------- w_src/w_dst = W2 @ a2 (per output channel c) ----------------
__global__ void k_wvec(const float* __restrict__ W2, const float* __restrict__ a2s,
                       const float* __restrict__ a2d, float* __restrict__ wsrc,
                       float* __restrict__ wdst){
  __shared__ float sm[8];
  int c = blockIdx.x, t = threadIdx.x;
  const float* row = W2 + (size_t)c*F_INF;
  float vs=0.f, vd=0.f;
  for (int f=t; f<F_INF; f+=256){ float v=row[f]; vs+=v*a2s[f]; vd+=v*a2d[f]; }
  #pragma unroll
  for (int o=32;o>0;o>>=1){ vs+=__shfl_down(vs,o); vd+=__shfl_down(vd,o); }
  int lane=t&63, w=t>>6;
  if (lane==0){ sm[w]=vs; sm[4+w]=vd; }
  __syncthreads();
  if (t==0) wsrc[c]=sm[0]+sm[1]+sm[2]+sm[3];
  if (t==1) wdst[c]=sm[4]+sm[5]+sm[6]+sm[7];
}

// ---- GAT1 (both branches), LDS-staged edges + 4-way ILP gather ----
__global__ void k_gat1(const float* __restrict__ h1st, const float* __restrict__ s_src,
                       const float* __restrict__ s_dst, const int* __restrict__ off,
                       const int* __restrict__ csr_src, const float* __restrict__ csr_w,
                       const float* __restrict__ b1, float* __restrict__ z,
                       float* __restrict__ za, const float* __restrict__ wsrc,
                       const float* __restrict__ wdst, float* __restrict__ ssz,
                       float* __restrict__ sdz){
  __shared__ int   sidx[256];
  __shared__ float scw[256];
  __shared__ float sev[256*4];
  __shared__ float smz[8];
  int nb = blockIdx.x, c = threadIdx.x, h = c>>6;
  int n = nb & (N_NODES-1), br = nb >> 12;
  const float* hm = h1st + (size_t)br*N_NODES*HIDC;
  const float* ssp = s_src + (size_t)br*N_NODES*4;
  const float* sdp = s_dst + (size_t)br*N_NODES*4;
  float* zp = br ? za : z;
  int o0 = off[n], o1 = off[n+1];
  int deg = o1 - o0;
  float4 sdv = *(const float4*)(sdp + (size_t)n*4);

  float m = -1e30f;
  for (int base=0; base<deg; base+=256){
    int cnt = min(256, deg-base);
    __syncthreads();
    if (c < cnt){
      int s = csr_src[o0+base+c];
      sidx[c] = s; scw[c] = csr_w[o0+base+c];
      float4 ss4 = *(const float4*)(ssp + (size_t)s*4);
      sev[c*4+0] = lrelu(ss4.x + sdv.x);
      sev[c*4+1] = lrelu(ss4.y + sdv.y);
      sev[c*4+2] = lrelu(ss4.z + sdv.z);
      sev[c*4+3] = lrelu(ss4.w + sdv.w);
    }
    __syncthreads();
    for (int t=0; t<cnt; t++) m = fmaxf(m, sev[t*4+h]);
  }

  const bool multi = deg > 256;
  float denom = 0.f, acc = 0.f;
  for (int base=0; base<deg; base+=256){
    int cnt = min(256, deg-base);
    if (multi){
      __syncthreads();
      if (c < cnt){
        int s = csr_src[o0+base+c];
        sidx[c] = s; scw[c] = csr_w[o0+base+c];
        float4 ss4 = *(const float4*)(ssp + (size_t)s*4);
        sev[c*4+0] = lrelu(ss4.x + sdv.x);
        sev[c*4+1] = lrelu(ss4.y + sdv.y);
        sev[c*4+2] = lrelu(ss4.z + sdv.z);
        sev[c*4+3] = lrelu(ss4.w + sdv.w);
      }
      __syncthreads();
    }
    int t = 0;
    for (; t+4 <= cnt; t += 4){
      int s0=sidx[t], s1=sidx[t+1], s2=sidx[t+2], s3=sidx[t+3];
      float w0 = __expf(sev[(t  )*4+h]-m)*scw[t  ];
      float w1 = __expf(sev[(t+1)*4+h]-m)*scw[t+1];
      float w2 = __expf(sev[(t+2)*4+h]-m)*scw[t+2];
      float w3 = __expf(sev[(t+3)*4+h]-m)*scw[t+3];
      float v0 = hm[(size_t)s0*HIDC+c];
      float v1 = hm[(size_t)s1*HIDC+c];
      float v2 = hm[(size_t)s2*HIDC+c];
      float v3 = hm[(size_t)s3*HIDC+c];
      denom += (w0+w1)+(w2+w3);
      acc += w0*v0 + w1*v1 + w2*v2 + w3*v3;
    }
    for (; t<cnt; ++t){
      int s0 = sidx[t];
      float w0 = __expf(sev[t*4+h]-m)*scw[t];
      denom += w0;
      acc += w0*hm[(size_t)s0*HIDC+c];
    }
  }

  float res = acc/(denom+1e-16f) + b1[c];
  float zv = fmaxf(res, 0.f);
  zp[(size_t)n*HIDC+c] = zv;
  if (br==0){
    float vs = zv*wsrc[c], vd = zv*wdst[c];
    #pragma unroll
    for (int o=32;o>0;o>>=1){ vs+=__shfl_down(vs,o); vd+=__shfl_down(vd,o); }
    int lane=c&63, w=c>>6;
    if (lane==0){ smz[w]=vs; smz[4+w]=vd; }
    __syncthreads();
    if (c==0) ssz[n]=smz[0]+smz[1]+smz[2]+smz[3];
    if (c==1) sdz[n]=smz[4]+smz[5]+smz[6]+smz[7];
  }
}

// ---- GAT2 aggregation on z (256-wide), same ILP structure ----
__global__ void k_gatz(const float* __restrict__ z, const float* __restrict__ ssz,
                       const float* __restrict__ sdz, const int* __restrict__ off,
                       const int* __restrict__ csr_src, const float* __restrict__ csr_w,
                       float* __restrict__ agg){
  __shared__ int   sidx[256];
  __shared__ float scw[256];
  __shared__ float sev[256];
  int n = blockIdx.x, c = threadIdx.x;
  int o0 = off[n], o1 = off[n+1];
  int deg = o1 - o0;
  float sd = sdz[n];

  float m = -1e30f;
  for (int base=0; base<deg; base+=256){
    int cnt = min(256, deg-base);
    __syncthreads();
    if (c < cnt){
      int s = csr_src[o0+base+c];
      sidx[c] = s; scw[c] = csr_w[o0+base+c];
      sev[c] = lrelu(ssz[s] + sd);
    }
    __syncthreads();
    for (int t=0; t<cnt; t++) m = fmaxf(m, sev[t]);
  }

  const bool multi = deg > 256;
  float denom = 0.f, acc = 0.f;
  for (int base=0; base<deg; base+=256){
    int cnt = min(256, deg-base);
    if (multi){
      __syncthreads();
      if (c < cnt){
        int s = csr_src[o0+base+c];
        sidx[c] = s; scw[c] = csr_w[o0+base+c];
        sev[c] = lrelu(ssz[s] + sd);
      }
      __syncthreads();
    }
    int t = 0;
    for (; t+4 <= cnt; t += 4){
      int s0=sidx[t], s1=sidx[t+1], s2=sidx[t+2], s3=sidx[t+3];
      float w0 = __expf(sev[t  ]-m)*scw[t  ];
      float w1 = __expf(sev[t+1]-m)*scw[t+1];
      float w2 = __expf(sev[t+2]-m)*scw[t+2];
      float w3 = __expf(sev[t+3]-m)*scw[t+3];
      float v0 = z[(size_t)s0*HIDC+c];
      float v1 = z[(size_t)s1*HIDC+c];
      float v2 = z[(size_t)s2*HIDC+c];
      float v3 = z[(size_t)s3*HIDC+c];
      denom += (w0+w1)+(w2+w3);
      acc += w0*v0 + w1*v1 + w2*v2 + w3*v3;
    }
    for (; t<cnt; ++t){
      int s0 = sidx[t];
      float w0 = __expf(sev[t]-m)*scw[t];
      denom += w0;
      acc += w0*z[(size_t)s0*HIDC+c];
    }
  }
  agg[(size_t)n*HIDC+c] = acc/(denom+1e-16f);
}

// ---------------- pooling: scores from Hp (single f32 slab) ----------------
__global__ void k_score(const float* __restrict__ Hp, const float* __restrict__ b1,
                        const float* __restrict__ w2, const float* __restrict__ b2,
                        float* __restrict__ sc){
  int row = blockIdx.x*4 + (threadIdx.x>>6);
  int lane = threadIdx.x & 63;
  size_t base = (size_t)row*POOLH;
  float h0 = fmaxf(Hp[base+lane]    + b1[lane],    0.f);
  float h1 = fmaxf(Hp[base+lane+64] + b1[lane+64], 0.f);
  float v = h0*w2[lane] + h1*w2[lane+64];
  #pragma unroll
  for (int o=32;o>0;o>>=1) v += __shfl_down(v,o);
  if (lane==0) sc[row] = v + b2[0];
}

__global__ void k_maxred2(const float* __restrict__ s, float* __restrict__ M){
  __shared__ float sm[16];
  int tid=threadIdx.x;
  const float* sp = s + (size_t)blockIdx.x*N_NODES;
  float m=-1e30f;
  for (int i=tid;i<N_NODES;i+=1024) m=fmaxf(m,sp[i]);
  #pragma unroll
  for (int o=32;o>0;o>>=1) m=fmaxf(m,__shfl_down(m,o));
  if ((tid&63)==0) sm[tid>>6]=m;
  __syncthreads();
  if (tid==0){
    float mm=sm[0];
    for (int i=1;i<16;i++) mm=fmaxf(mm,sm[i]);
    M[blockIdx.x]=mm;
  }
}

__global__ void k_p2(const float* __restrict__ sc, const float* __restrict__ M,
                     float* __restrict__ pA, float* __restrict__ pB,
                     u16* __restrict__ qT){
  int i = blockIdx.x*256+threadIdx.x;
  float a = __expf(sc[i]-M[0]);
  float b = __expf(sc[N_NODES+i]-M[1]);
  pA[i]=a; pB[i]=b;
  qT[(size_t)512*N_NODES+i]=f2b(a);
  qT[(size_t)513*N_NODES+i]=f2b(b);
}

// sums 4 split-K bf16 slabs of G [4096][576]; dn cols 512/513; norm + sigmoid
__global__ void k_gfin(const u16* __restrict__ G, float* __restrict__ gA,
                       float* __restrict__ gB){
  __shared__ float sm[4];
  __shared__ float tot;
  const size_t SL = (size_t)N_NODES*GCOLS;
  int n=blockIdx.x, c=threadIdx.x;
  int brv = blockIdx.y;
  int co = brv ? HIDC : 0, dcol = brv ? 513 : 512;
  float* g = brv ? gB : gA;
  size_t base = (size_t)n*GCOLS;
  float gp=0.f, dn=0.f;
  #pragma unroll
  for (int s=0;s<4;s++){ gp += b2f(G[base+co+c+s*SL]); dn += b2f(G[base+dcol+s*SL]); }
  gp /= (dn + 1e-16f);
  float v = gp*gp;
  #pragma unroll
  for (int o=32;o>0;o>>=1) v+=__shfl_down(v,o);
  if ((c&63)==0) sm[c>>6]=v;
  __syncthreads();
  if (c==0) tot = sm[0]+sm[1]+sm[2]+sm[3];
  __syncthreads();
  float nrm = sqrtf(tot);
  float x = gp/fmaxf(nrm,1e-12f);
  g[(size_t)n*HIDC+c]=1.f/(1.f+__expf(-x));
}

// ---------------- discriminator ----------------
__global__ void k_disc(const float* __restrict__ z, const float* __restrict__ za,
                       const float* __restrict__ V, const float* __restrict__ Va,
                       const float* __restrict__ bbp, const float* __restrict__ biasp,
                       float* __restrict__ ret, float* __restrict__ ret_a){
  __shared__ float sm[16];
  int n=blockIdx.x, c=threadIdx.x;
  float ez = z[(size_t)n*HIDC+c], ea = za[(size_t)n*HIDC+c];
  float v  = V[(size_t)n*HIDC+c], va = Va[(size_t)n*HIDC+c];
  float p1=ez*v, p2=ea*v, p3=ea*va, p4=ez*va;
  #pragma unroll
  for (int o=32;o>0;o>>=1){
    p1+=__shfl_down(p1,o); p2+=__shfl_down(p2,o);
    p3+=__shfl_down(p3,o); p4+=__shfl_down(p4,o);
  }
  int lane=c&63, w=c>>6;
  if (lane==0){ sm[w]=p1; sm[4+w]=p2; sm[8+w]=p3; sm[12+w]=p4; }
  __syncthreads();
  if (c==0){
    float add = bbp[0]+biasp[0];
    ret[n*2+0]   = sm[0]+sm[1]+sm[2]+sm[3]   + add;
    ret[n*2+1]   = sm[4]+sm[5]+sm[6]+sm[7]   + add;
    ret_a[n*2+0] = sm[8]+sm[9]+sm[10]+sm[11] + add;
    ret_a[n*2+1] = sm[12]+sm[13]+sm[14]+sm[15] + add;
  }
}

extern "C" void kernel_launch(void* const* d_in, const int* in_sizes, int n_in,
                              void* d_out, int out_size, void* d_ws, size_t ws_size,
                              hipStream_t stream){
  (void)in_sizes; (void)n_in; (void)out_size; (void)ws_size;
  const float* feat   = (const float*)d_in[0];
  const float* feat_a = (const float*)d_in[1];
  const int*   ei     = (const int*)d_in[2];
  const float* ew     = (const float*)d_in[3];
  const int*   mask   = (const int*)d_in[4];
  const float* W1     = (const float*)d_in[5];
  const float* a_src1 = (const float*)d_in[6];
  const float* a_dst1 = (const float*)d_in[7];
  const float* b1     = (const float*)d_in[8];
  const float* W2     = (const float*)d_in[9];
  const float* a_src2 = (const float*)d_in[10];
  const float* a_dst2 = (const float*)d_in[11];
  const float* b2     = (const float*)d_in[12];
  const float* pw1    = (const float*)d_in[13];
  const float* pb1    = (const float*)d_in[14];
  const float* pw2    = (const float*)d_in[15];
  const float* pb2    = (const float*)d_in[16];
  const float* dw     = (const float*)d_in[17];
  const float* dbb    = (const float*)d_in[18];
  const float* dbias  = (const float*)d_in[19];

  float* out  = (float*)d_out;
  float* z    = out;
  float* hout = out + (size_t)N_NODES*HIDC;
  float* ret  = hout + (size_t)N_NODES*F_INF;
  float* ret_a= ret + (size_t)N_NODES*2;

  char* cur = (char*)d_ws;
  auto alloc = [&](size_t bytes)->void*{
    void* p = cur; cur += (bytes + 255) & ~(size_t)255; return p;
  };
  // SLB: time-shared — proj bf16 slabs (16.8MB) -> mask bf16 slabs (18.9MB)
  void* SLB = alloc((size_t)4*N_NODES*GCOLS*4);
  u16* W1T  = (u16*)alloc((size_t)HIDC*FPAD*2);
  u16* W2T  = (u16*)alloc((size_t)NPAD*HIDC*2);
  u16* pw1T = (u16*)alloc((size_t)POOLH*HIDC*2);
  u16* qT   = (u16*)alloc((size_t)GCOLS*N_NODES*2);
  u16* dwb  = (u16*)alloc((size_t)HIDC*HIDC*2);
  float* h1st = (float*)alloc((size_t)2*N_NODES*HIDC*4);
  float* za   = (float*)alloc((size_t)N_NODES*HIDC*4);
  float* agg  = (float*)alloc((size_t)N_NODES*HIDC*4);
  float* Vst  = (float*)alloc((size_t)2*N_NODES*HIDC*4); // Hp, then V;Va
  float* gv   = (float*)alloc((size_t)N_NODES*HIDC*4);
  float* gva  = (float*)alloc((size_t)N_NODES*HIDC*4);
  float* ss1 = (float*)alloc((size_t)2*N_NODES*4*4);
  float* sd1 = (float*)alloc((size_t)2*N_NODES*4*4);
  float* ssz = (float*)alloc(N_NODES*4);
  float* sdz = (float*)alloc(N_NODES*4);
  float* wsrc= (float*)alloc(HIDC*4);
  float* wdst= (float*)alloc(HIDC*4);
  float* scAB = (float*)alloc((size_t)2*N_NODES*4);
  float* pvA = (float*)alloc(N_NODES*4);
  float* pvB = (float*)alloc(N_NODES*4);
  float* Mb  = (float*)alloc(256);
  int* deg    = (int*)alloc(N_NODES*4);
  int* off    = (int*)alloc((N_NODES+64)*4);
  int* cursor = (int*)alloc(N_NODES*4);
  int* csrc   = (int*)alloc(NEDGE*4);
  float* csw  = (float*)alloc(NEDGE*4);

  float* V   = Vst;
  float* Va  = Vst + (size_t)N_NODES*HIDC;

  // ---- CSR build + independent small prep ----
  hipMemsetAsync(deg, 0, N_NODES*sizeof(int), stream);
  hipMemsetAsync(cursor, 0, N_NODES*sizeof(int), stream);
  hipMemsetAsync(qT + (size_t)514*N_NODES, 0, (size_t)(GCOLS-514)*N_NODES*2, stream);
  k_deg<<<NEDGE/256,256,0,stream>>>(ei+NEDGE, deg);
  k_scan<<<1,1024,0,stream>>>(deg, off);
  k_fill<<<NEDGE/256,256,0,stream>>>(ei, ew, off, cursor, csrc, csw);
  k_wvec<<<HIDC,256,0,stream>>>(W2, a_src2, a_dst2, wsrc, wdst);

  // ---- weight conversions ----
  k_trcvt<<<dim3(HIDC/32, FPAD/32),256,0,stream>>>(W1, W1T, F_INF, HIDC, FPAD, nullptr);
  k_trcvt<<<dim3(NPAD/32, HIDC/32),256,0,stream>>>(W2, W2T, HIDC, F_INF, HIDC, nullptr);
  k_trcvt<<<dim3(POOLH/32, HIDC/32),256,0,stream>>>(pw1, pw1T, HIDC, POOLH, HIDC, nullptr);
  k_cvt<<<HIDC*HIDC/4/256,256,0,stream>>>(dw, dwb, HIDC, HIDC, HIDC);

  // ---- stacked projection: BM=256, BN=128, split-K=4, bf16 slabs ----
  // Staged volume ~148MB (A once + B x32). 256 blocks, 160KB LDS.
  k_mg<0,256,128,4,2,1><<<dim3(2*N_NODES/256, HIDC/128, 4),512,0,stream>>>(
      feat, feat_a, N_NODES, W1T, SLB, nullptr,
      2*N_NODES, HIDC, FPAD, F_INF, F_INF, FPAD, HIDC, 768);
  k_hred<<<2*N_NODES,256,0,stream>>>((const u16*)SLB, h1st, a_src1, a_dst1, ss1, sd1);

  // ---- GAT1 both branches + fused GAT2 scores ----
  k_gat1<<<2*N_NODES,256,0,stream>>>(h1st, ss1, sd1, off, csrc, csw, b1, z, za,
                                     wsrc, wdst, ssz, sdz);

  // ---- GAT2: aggregate z, then hout = agg @ W2 + b2 ----
  k_gatz<<<N_NODES,256,0,stream>>>(z, ssz, sdz, off, csrc, csw, agg);
  k_mg<0,64,64,2,2,0><<<dim3(N_NODES/64, FPAD/64, 1),256,0,stream>>>(
      agg, agg, N_NODES, W2T, hout, b2,
      N_NODES, F_INF, HIDC, HIDC, HIDC, HIDC, F_INF, HIDC);

  // ---- pooling MLP as GEMM: Hp = [z;za] @ pw1 ----
  k_mg<0,64,64,2,2,0><<<dim3(2*N_NODES/64, POOLH/64, 1),256,0,stream>>>(
      z, za, N_NODES, pw1T, Vst, nullptr,
      2*N_NODES, POOLH, HIDC, HIDC, HIDC, HIDC, POOLH, HIDC);
  k_score<<<2*N_NODES/4,256,0,stream>>>(Vst, pb1, pw2, pb2, scAB);
  k_maxred2<<<2,1024,0,stream>>>(scAB, Mb);
  k_p2<<<N_NODES/256,256,0,stream>>>(scAB, Mb, pvA, pvB, qT);
  k_trcvt<<<dim3(HIDC/32, N_NODES/32),256,0,stream>>>(z,  qT, N_NODES, HIDC, N_NODES, pvA);
  k_trcvt<<<dim3(HIDC/32, N_NODES/32),256,0,stream>>>(za, qT + (size_t)HIDC*N_NODES, N_NODES, HIDC, N_NODES, pvB);

  // ---- masked-softmax GEMM: G = Mask @ [q | qa | pA | pB] ----
  // BM=128, BN=192, split-K=4: staged ~352MB (was ~503). 384 blocks, 112KB LDS.
  k_mg<1,128,192,2,4,1><<<dim3(N_NODES/128, GCOLS/192, 4),512,0,stream>>>(
      mask, mask, 2*N_NODES, qT, SLB, nullptr,
      N_NODES, GCOLS, N_NODES, N_NODES, N_NODES, N_NODES, GCOLS, 1024);
  k_gfin<<<dim3(N_NODES,2),256,0,stream>>>((const u16*)SLB, gv, gva);

  // ---- discriminator: [V;Va] = [gv;gva] @ dw^T ----
  k_mg<0,64,64,2,2,0><<<dim3(2*N_NODES/64, HIDC/64, 1),256,0,stream>>>(
      gv, gva, N_NODES, dwb, Vst, nullptr,
      2*N_NODES, HIDC, HIDC, HIDC, HIDC, HIDC, HIDC, HIDC);
  k_disc<<<N_NODES,256,0,stream>>>(z, za, V, Va, dbb, dbias, ret, ret_a);
}

// Round 17
// 224.839 us; speedup vs baseline: 1.0768x; 1.0768x over previous
//
#include <hip/hip_runtime.h>
#include <cstdint>
#include <cstddef>

#define N_NODES 4096
#define F_INF   3000
#define FPAD    3008
#define NPAD    3072
#define HIDC    256
#define NEDGE   65536
#define POOLH   128
#define GCOLS   576   // 256 (branch1) + 256 (branchA) + dnA + dnB + pad

typedef unsigned short u16;
typedef __attribute__((ext_vector_type(8))) short bf16x8;
typedef __attribute__((ext_vector_type(8))) unsigned short us8;
typedef __attribute__((ext_vector_type(4))) unsigned int u32x4;
typedef __attribute__((ext_vector_type(4))) float f32x4;

__device__ inline float lrelu(float x){ return x > 0.f ? x : 0.2f*x; }
__device__ inline u16 f2b(float f){
  uint32_t x = __builtin_bit_cast(uint32_t, f);
  uint32_t r = (x + 0x7fffu + ((x >> 16) & 1u)) >> 16;
  return (u16)r;
}
__device__ inline float b2f(u16 u){
  uint32_t x = ((uint32_t)u) << 16;
  return __builtin_bit_cast(float, x);
}
// packed f32x2 -> bf16x2 (RTNE), one instruction
__device__ __forceinline__ uint32_t cvt2(float lo, float hi){
  uint32_t r;
  asm("v_cvt_pk_bf16_f32 %0, %1, %2" : "=v"(r) : "v"(lo), "v"(hi));
  return r;
}
__device__ __forceinline__ void lds16(const void* g, void* l){
  __builtin_amdgcn_global_load_lds((const __attribute__((address_space(1))) void*)g,
                                   (__attribute__((address_space(3))) void*)l, 16, 0, 0);
}

// ---------------- CSR build ----------------
__global__ void k_deg(const int* __restrict__ dst, int* __restrict__ deg){
  int e = blockIdx.x*256 + threadIdx.x;
  if (e < NEDGE) atomicAdd(&deg[dst[e]], 1);
}

__global__ void k_scan(const int* __restrict__ deg, int* __restrict__ off){
  __shared__ int sm[1024];
  int tid = threadIdx.x;
  int v0=deg[tid*4], v1=deg[tid*4+1], v2=deg[tid*4+2], v3=deg[tid*4+3];
  int s = v0+v1+v2+v3;
  sm[tid]=s; __syncthreads();
  for (int d=1; d<1024; d<<=1){
    int t = (tid>=d)? sm[tid-d] : 0;
    __syncthreads();
    sm[tid] += t;
    __syncthreads();
  }
  int run = sm[tid]-s;
  off[tid*4+0]=run; run+=v0;
  off[tid*4+1]=run; run+=v1;
  off[tid*4+2]=run; run+=v2;
  off[tid*4+3]=run; run+=v3;
  if (tid==1023) off[N_NODES]=run;
}

__global__ void k_fill(const int* __restrict__ ei, const float* __restrict__ ew,
                       const int* __restrict__ off, int* __restrict__ cursor,
                       int* __restrict__ csr_src, float* __restrict__ csr_w){
  int e = blockIdx.x*256+threadIdx.x;
  if (e >= NEDGE) return;
  int d = ei[NEDGE + e];
  int slot = off[d] + atomicAdd(&cursor[d],1);
  csr_src[slot] = ei[e];
  csr_w[slot] = ew[e];
}

// ---------------- conversions ----------------
__global__ void k_cvt(const float* __restrict__ in, u16* __restrict__ out,
                      int R, int Cin, int Cout){
  size_t i = ((size_t)blockIdx.x*256 + threadIdx.x)*4;
  if (i >= (size_t)R*Cout) return;
  int r = (int)(i / Cout), c = (int)(i % Cout);
  ushort4 o;
  if (c + 3 < Cin){
    float4 v = *(const float4*)(in + (size_t)r*Cin + c);
    o.x=f2b(v.x); o.y=f2b(v.y); o.z=f2b(v.z); o.w=f2b(v.w);
  } else {
    float vs[4];
    #pragma unroll
    for (int j=0;j<4;j++) vs[j] = (c+j<Cin)? in[(size_t)r*Cin+c+j] : 0.f;
    o.x=f2b(vs[0]); o.y=f2b(vs[1]); o.z=f2b(vs[2]); o.w=f2b(vs[3]);
  }
  *(ushort4*)(out+i) = o;
}

// out[c][r] = in[r][c] * (scale?scale[r]:1), bf16, zero-pad outside [R][C].
__global__ void k_trcvt(const float* __restrict__ in, u16* __restrict__ out,
                        int R, int C, int OCols, const float* __restrict__ scale){
  __shared__ float t[32][33];
  int c0 = blockIdx.x*32, r0 = blockIdx.y*32;
  int tx = threadIdx.x & 31, ty = threadIdx.x >> 5;
  #pragma unroll
  for (int i=0;i<4;i++){
    int r = r0 + ty + i*8, c = c0 + tx;
    float v = (r<R && c<C) ? in[(size_t)r*C + c] : 0.f;
    if (scale && r<R) v *= scale[r];
    t[ty+i*8][tx] = v;
  }
  __syncthreads();
  #pragma unroll
  for (int i=0;i<4;i++){
    int c = c0 + ty + i*8, r = r0 + tx;
    out[(size_t)c*OCols + r] = f2b(t[tx][ty+i*8]);
  }
}

// ------- MFMA GEMM: gload_lds + counted-vmcnt 2-deep pipeline (T3/T4) -------
// C[M,N] = A[M,K] @ B^T. B [N][ldb] bf16, zero for k in [Ksrc, K). K mult 64.
// BK=64 (conflict-free swizzle: A chunk c^(row&15), B c^(row&7)).
// A chunks with gk+4 > Ksrc clamp to row start (garbage x zero-B = 0), keeping
// the per-stage load count uniform. A staged raw f32/i32 (ATYPE 0/1) via
// global_load_lds w/ XOR-source-swizzle + linear dest; bf16-cvt at read.
// CT: 0 = f32 out (+bias), 1 = bf16 out. grid (M/BM, N/BN, SPLITK).
template<int ATYPE, int BM, int BN, int NWM, int NWN, int CT>
__global__ __launch_bounds__(NWM*NWN*64) void k_mg(
    const void* __restrict__ A0v, const void* __restrict__ A1v, int srow,
    const u16* __restrict__ B, void* __restrict__ Cv,
    const float* __restrict__ bias,
    int M, int nmax, int K, int Ksrc,
    int lda, int ldb, int ldc, int kcount){
  constexpr int THREADS = NWM*NWN*64;
  constexpr int WM = BM/NWM, WN = BN/NWN, MR = WM/16, NR = WN/16;
  constexpr int APT = (BM*16)/THREADS, BPT = (BN*8)/THREADS;
  constexpr int LPT = APT + BPT;
  constexpr int ABYTES = BM*64*4, BBYTES = BN*64*2;
  __shared__ __align__(16) char L[2*ABYTES + 2*BBYTES];
  const int tid = threadIdx.x;
  const int bm = blockIdx.x*BM, bn = blockIdx.y*BN;
  const int lane = tid & 63, w = tid >> 6;
  const int wr = w / NWN, wc = w % NWN;
  f32x4 acc[MR][NR] = {};

  const int kbeg = blockIdx.z * kcount;
  const int kend = min(K, kbeg + kcount);
  const int nsteps = (kend - kbeg) >> 6;

  auto stage = [&](int kk, int half){
    char* bufA = L + half*ABYTES;
    #pragma unroll
    for (int p=0;p<APT;p++){
      int s = p*THREADS + tid, row = s>>4, c = s&15, cg = c ^ (row&15);
      int gk = kk + cg*4;
      if (gk + 4 > Ksrc) gk = 0;           // clamp: garbage * zero-B = 0
      int grow = bm + row;
      const char* Ap = (grow < srow)
          ? (const char*)A0v + ((size_t)grow*lda + gk)*4
          : (const char*)A1v + ((size_t)(grow-srow)*lda + gk)*4;
      lds16(Ap, bufA + (size_t)s*16);
    }
    char* bufB = L + 2*ABYTES + half*BBYTES;
    #pragma unroll
    for (int p=0;p<BPT;p++){
      int s = p*THREADS + tid, row = s>>3, c = s&7, cg = c ^ (row&7);
      lds16(B + (size_t)(bn+row)*ldb + kk + cg*8, bufB + (size_t)s*16);
    }
  };

  auto compute = [&](int half){
    char* bufA = L + half*ABYTES;
    char* bufB = L + 2*ABYTES + half*BBYTES;
    #pragma unroll
    for (int ks=0; ks<2; ks++){
      bf16x8 af[MR], bfv[NR];
      #pragma unroll
      for (int m=0;m<MR;m++){
        int row = wr*WM + m*16 + (lane&15);
        int g = ks*8 + (lane>>4)*2;
        int xa = row & 15;
        f32x4 a0 = *(const f32x4*)(bufA + row*256 + (((g  )^xa)<<4));
        f32x4 a1 = *(const f32x4*)(bufA + row*256 + (((g+1)^xa)<<4));
        u32x4 o;
        if (ATYPE==0){
          o[0]=cvt2(a0[0],a0[1]); o[1]=cvt2(a0[2],a0[3]);
          o[2]=cvt2(a1[0],a1[1]); o[3]=cvt2(a1[2],a1[3]);
        } else {
          u32x4 ia = __builtin_bit_cast(u32x4, a0);
          u32x4 ib = __builtin_bit_cast(u32x4, a1);
          o[0] = ia[0]*0x3F80u + ia[1]*0x3F800000u;
          o[1] = ia[2]*0x3F80u + ia[3]*0x3F800000u;
          o[2] = ib[0]*0x3F80u + ib[1]*0x3F800000u;
          o[3] = ib[2]*0x3F80u + ib[3]*0x3F800000u;
        }
        af[m] = __builtin_bit_cast(bf16x8, o);
      }
      #pragma unroll
      for (int n=0;n<NR;n++){
        int row = wc*WN + n*16 + (lane&15);
        int g = ks*4 + (lane>>4);
        bfv[n] = *(const bf16x8*)(bufB + row*128 + ((g ^ (row&7))<<4));
      }
      #pragma unroll
      for (int m=0;m<MR;m++)
        #pragma unroll
        for (int n=0;n<NR;n++)
          acc[m][n] = __builtin_amdgcn_mfma_f32_16x16x32_bf16(af[m], bfv[n], acc[m][n], 0,0,0);
    }
  };

  // prologue: 2 tiles in flight
  stage(kbeg, 0);
  if (nsteps > 1) stage(kbeg + 64, 1);

  for (int t=0; t<nsteps; ++t){
    if (t+1 < nsteps){
      if constexpr (LPT == 3)       asm volatile("s_waitcnt vmcnt(3)" ::: "memory");
      else if constexpr (LPT == 4)  asm volatile("s_waitcnt vmcnt(4)" ::: "memory");
      else if constexpr (LPT == 5)  asm volatile("s_waitcnt vmcnt(5)" ::: "memory");
      else if constexpr (LPT == 6)  asm volatile("s_waitcnt vmcnt(6)" ::: "memory");
      else if constexpr (LPT == 7)  asm volatile("s_waitcnt vmcnt(7)" ::: "memory");
      else if constexpr (LPT == 8)  asm volatile("s_waitcnt vmcnt(8)" ::: "memory");
      else if constexpr (LPT == 10) asm volatile("s_waitcnt vmcnt(10)" ::: "memory");
      else                          asm volatile("s_waitcnt vmcnt(0)" ::: "memory");
    } else {
      asm volatile("s_waitcnt vmcnt(0)" ::: "memory");
    }
    __builtin_amdgcn_s_barrier();
    __builtin_amdgcn_sched_barrier(0);     // pin ds_reads below the wait
    compute(t & 1);
    __builtin_amdgcn_s_barrier();          // all waves done reading buf(t&1)
    if (t+2 < nsteps) stage(kbeg + (t+2)*64, t & 1);
  }

  const size_t slab = (size_t)blockIdx.z * (size_t)M * ldc;
  const int rbase = bm + wr*WM + ((lane>>4)<<2);
  const int cbase = bn + wc*WN + (lane&15);
  if constexpr (CT == 1){
    u16* C = (u16*)Cv + slab;
    #pragma unroll
    for (int n=0;n<NR;n++){
      int gcol = cbase + n*16;
      if (gcol >= nmax) continue;
      #pragma unroll
      for (int m=0;m<MR;m++)
        #pragma unroll
        for (int j=0;j<4;j++)
          C[(size_t)(rbase + m*16 + j)*ldc + gcol] = f2b(acc[m][n][j]);
    }
  } else {
    float* C = (float*)Cv + slab;
    #pragma unroll
    for (int n=0;n<NR;n++){
      int gcol = cbase + n*16;
      if (gcol >= nmax) continue;
      float bv = bias ? bias[gcol] : 0.f;
      #pragma unroll
      for (int m=0;m<MR;m++)
        #pragma unroll
        for (int j=0;j<4;j++)
          C[(size_t)(rbase + m*16 + j)*ldc + gcol] = acc[m][n][j] + bv;
    }
  }
}

// ------- proj slab-reduce (4 bf16 slabs) fused with GAT1 scores -------
__global__ void k_hred(const u16* __restrict__ S, float* __restrict__ h,
                       const float* __restrict__ a_src, const float* __restrict__ a_dst,
                       float* __restrict__ ss, float* __restrict__ sd){
  const size_t SLP = (size_t)2*N_NODES*HIDC;
  int n = blockIdx.x, c = threadIdx.x;
  size_t i = (size_t)n*HIDC + c;
  float v = b2f(S[i]) + b2f(S[i+SLP]) + b2f(S[i+2*SLP]) + b2f(S[i+3*SLP]);
  h[i] = v;
  float vs = v*a_src[c], vd = v*a_dst[c];
  #pragma unroll
  for (int o=32;o>0;o>>=1){ vs += __shfl_down(vs,o); vd += __shfl_down(vd,o); }
  if ((c&63)==0){ int hh=c>>6; ss[n*4+hh]=vs; sd[n*4+hh]=vd; }
}

// ---------------- w_src/w_dst = W2 @ a2 (per output channel c) ----------------
__global__ void k_wvec(const float* __restrict__ W2, const float* __restrict__ a2s,
                       const float* __restrict__ a2d, float* __restrict__ wsrc,
                       float* __restrict__ wdst){
  __shared__ float sm[8];
  int c = blockIdx.x, t = threadIdx.x;
  const float* row = W2 + (size_t)c*F_INF;
  float vs=0.f, vd=0.f;
  for (int f=t; f<F_INF; f+=256){ float v=row[f]; vs+=v*a2s[f]; vd+=v*a2d[f]; }
  #pragma unroll
  for (int o=32;o>0;o>>=1){ vs+=__shfl_down(vs,o); vd+=__shfl_down(vd,o); }
  int lane=t&63, w=t>>6;
  if (lane==0){ sm[w]=vs; sm[4+w]=vd; }
  __syncthreads();
  if (t==0) wsrc[c]=sm[0]+sm[1]+sm[2]+sm[3];
  if (t==1) wdst[c]=sm[4]+sm[5]+sm[6]+sm[7];
}

// ---- GAT1 (both branches), LDS-staged edges + 4-way ILP gather ----
__global__ void k_gat1(const float* __restrict__ h1st, const float* __restrict__ s_src,
                       const float* __restrict__ s_dst, const int* __restrict__ off,
                       const int* __restrict__ csr_src, const float* __restrict__ csr_w,
                       const float* __restrict__ b1, float* __restrict__ z,
                       float* __restrict__ za, const float* __restrict__ wsrc,
                       const float* __restrict__ wdst, float* __restrict__ ssz,
                       float* __restrict__ sdz){
  __shared__ int   sidx[256];
  __shared__ float scw[256];
  __shared__ float sev[256*4];
  __shared__ float smz[8];
  int nb = blockIdx.x, c = threadIdx.x, h = c>>6;
  int n = nb & (N_NODES-1), br = nb >> 12;
  const float* hm = h1st + (size_t)br*N_NODES*HIDC;
  const float* ssp = s_src + (size_t)br*N_NODES*4;
  const float* sdp = s_dst + (size_t)br*N_NODES*4;
  float* zp = br ? za : z;
  int o0 = off[n], o1 = off[n+1];
  int deg = o1 - o0;
  float4 sdv = *(const float4*)(sdp + (size_t)n*4);

  float m = -1e30f;
  for (int base=0; base<deg; base+=256){
    int cnt = min(256, deg-base);
    __syncthreads();
    if (c < cnt){
      int s = csr_src[o0+base+c];
      sidx[c] = s; scw[c] = csr_w[o0+base+c];
      float4 ss4 = *(const float4*)(ssp + (size_t)s*4);
      sev[c*4+0] = lrelu(ss4.x + sdv.x);
      sev[c*4+1] = lrelu(ss4.y + sdv.y);
      sev[c*4+2] = lrelu(ss4.z + sdv.z);
      sev[c*4+3] = lrelu(ss4.w + sdv.w);
    }
    __syncthreads();
    for (int t=0; t<cnt; t++) m = fmaxf(m, sev[t*4+h]);
  }

  const bool multi = deg > 256;
  float denom = 0.f, acc = 0.f;
  for (int base=0; base<deg; base+=256){
    int cnt = min(256, deg-base);
    if (multi){
      __syncthreads();
      if (c < cnt){
        int s = csr_src[o0+base+c];
        sidx[c] = s; scw[c] = csr_w[o0+base+c];
        float4 ss4 = *(const float4*)(ssp + (size_t)s*4);
        sev[c*4+0] = lrelu(ss4.x + sdv.x);
        sev[c*4+1] = lrelu(ss4.y + sdv.y);
        sev[c*4+2] = lrelu(ss4.z + sdv.z);
        sev[c*4+3] = lrelu(ss4.w + sdv.w);
      }
      __syncthreads();
    }
    int t = 0;
    for (; t+4 <= cnt; t += 4){
      int s0=sidx[t], s1=sidx[t+1], s2=sidx[t+2], s3=sidx[t+3];
      float w0 = __expf(sev[(t  )*4+h]-m)*scw[t  ];
      float w1 = __expf(sev[(t+1)*4+h]-m)*scw[t+1];
      float w2 = __expf(sev[(t+2)*4+h]-m)*scw[t+2];
      float w3 = __expf(sev[(t+3)*4+h]-m)*scw[t+3];
      float v0 = hm[(size_t)s0*HIDC+c];
      float v1 = hm[(size_t)s1*HIDC+c];
      float v2 = hm[(size_t)s2*HIDC+c];
      float v3 = hm[(size_t)s3*HIDC+c];
      denom += (w0+w1)+(w2+w3);
      acc += w0*v0 + w1*v1 + w2*v2 + w3*v3;
    }
    for (; t<cnt; ++t){
      int s0 = sidx[t];
      float w0 = __expf(sev[t*4+h]-m)*scw[t];
      denom += w0;
      acc += w0*hm[(size_t)s0*HIDC+c];
    }
  }

  float res = acc/(denom+1e-16f) + b1[c];
  float zv = fmaxf(res, 0.f);
  zp[(size_t)n*HIDC+c] = zv;
  if (br==0){
    float vs = zv*wsrc[c], vd = zv*wdst[c];
    #pragma unroll
    for (int o=32;o>0;o>>=1){ vs+=__shfl_down(vs,o); vd+=__shfl_down(vd,o); }
    int lane=c&63, w=c>>6;
    if (lane==0){ smz[w]=vs; smz[4+w]=vd; }
    __syncthreads();
    if (c==0) ssz[n]=smz[0]+smz[1]+smz[2]+smz[3];
    if (c==1) sdz[n]=smz[4]+smz[5]+smz[6]+smz[7];
  }
}

// ---- GAT2 aggregation on z (256-wide), same ILP structure ----
__global__ void k_gatz(const float* __restrict__ z, const float* __restrict__ ssz,
                       const float* __restrict__ sdz, const int* __restrict__ off,
                       const int* __restrict__ csr_src, const float* __restrict__ csr_w,
                       float* __restrict__ agg){
  __shared__ int   sidx[256];
  __shared__ float scw[256];
  __shared__ float sev[256];
  int n = blockIdx.x, c = threadIdx.x;
  int o0 = off[n], o1 = off[n+1];
  int deg = o1 - o0;
  float sd = sdz[n];

  float m = -1e30f;
  for (int base=0; base<deg; base+=256){
    int cnt = min(256, deg-base);
    __syncthreads();
    if (c < cnt){
      int s = csr_src[o0+base+c];
      sidx[c] = s; scw[c] = csr_w[o0+base+c];
      sev[c] = lrelu(ssz[s] + sd);
    }
    __syncthreads();
    for (int t=0; t<cnt; t++) m = fmaxf(m, sev[t]);
  }

  const bool multi = deg > 256;
  float denom = 0.f, acc = 0.f;
  for (int base=0; base<deg; base+=256){
    int cnt = min(256, deg-base);
    if (multi){
      __syncthreads();
      if (c < cnt){
        int s = csr_src[o0+base+c];
        sidx[c] = s; scw[c] = csr_w[o0+base+c];
        sev[c] = lrelu(ssz[s] + sd);
      }
      __syncthreads();
    }
    int t = 0;
    for (; t+4 <= cnt; t += 4){
      int s0=sidx[t], s1=sidx[t+1], s2=sidx[t+2], s3=sidx[t+3];
      float w0 = __expf(sev[t  ]-m)*scw[t  ];
      float w1 = __expf(sev[t+1]-m)*scw[t+1];
      float w2 = __expf(sev[t+2]-m)*scw[t+2];
      float w3 = __expf(sev[t+3]-m)*scw[t+3];
      float v0 = z[(size_t)s0*HIDC+c];
      float v1 = z[(size_t)s1*HIDC+c];
      float v2 = z[(size_t)s2*HIDC+c];
      float v3 = z[(size_t)s3*HIDC+c];
      denom += (w0+w1)+(w2+w3);
      acc += w0*v0 + w1*v1 + w2*v2 + w3*v3;
    }
    for (; t<cnt; ++t){
      int s0 = sidx[t];
      float w0 = __expf(sev[t]-m)*scw[t];
      denom += w0;
      acc += w0*z[(size_t)s0*HIDC+c];
    }
  }
  agg[(size_t)n*HIDC+c] = acc/(denom+1e-16f);
}

// ---------------- pooling: scores from Hp (single f32 slab) ----------------
__global__ void k_score(const float* __restrict__ Hp, const float* __restrict__ b1,
                        const float* __restrict__ w2, const float* __restrict__ b2,
                        float* __restrict__ sc){
  int row = blockIdx.x*4 + (threadIdx.x>>6);
  int lane = threadIdx.x & 63;
  size_t base = (size_t)row*POOLH;
  float h0 = fmaxf(Hp[base+lane]    + b1[lane],    0.f);
  float h1 = fmaxf(Hp[base+lane+64] + b1[lane+64], 0.f);
  float v = h0*w2[lane] + h1*w2[lane+64];
  #pragma unroll
  for (int o=32;o>0;o>>=1) v += __shfl_down(v,o);
  if (lane==0) sc[row] = v + b2[0];
}

__global__ void k_maxred2(const float* __restrict__ s, float* __restrict__ M){
  __shared__ float sm[16];
  int tid=threadIdx.x;
  const float* sp = s + (size_t)blockIdx.x*N_NODES;
  float m=-1e30f;
  for (int i=tid;i<N_NODES;i+=1024) m=fmaxf(m,sp[i]);
  #pragma unroll
  for (int o=32;o>0;o>>=1) m=fmaxf(m,__shfl_down(m,o));
  if ((tid&63)==0) sm[tid>>6]=m;
  __syncthreads();
  if (tid==0){
    float mm=sm[0];
    for (int i=1;i<16;i++) mm=fmaxf(mm,sm[i]);
    M[blockIdx.x]=mm;
  }
}

__global__ void k_p2(const float* __restrict__ sc, const float* __restrict__ M,
                     float* __restrict__ pA, float* __restrict__ pB,
                     u16* __restrict__ qT){
  int i = blockIdx.x*256+threadIdx.x;
  float a = __expf(sc[i]-M[0]);
  float b = __expf(sc[N_NODES+i]-M[1]);
  pA[i]=a; pB[i]=b;
  qT[(size_t)512*N_NODES+i]=f2b(a);
  qT[(size_t)513*N_NODES+i]=f2b(b);
}

// sums 4 split-K bf16 slabs of G [4096][576]; dn cols 512/513; norm + sigmoid
__global__ void k_gfin(const u16* __restrict__ G, float* __restrict__ gA,
                       float* __restrict__ gB){
  __shared__ float sm[4];
  __shared__ float tot;
  const size_t SL = (size_t)N_NODES*GCOLS;
  int n=blockIdx.x, c=threadIdx.x;
  int brv = blockIdx.y;
  int co = brv ? HIDC : 0, dcol = brv ? 513 : 512;
  float* g = brv ? gB : gA;
  size_t base = (size_t)n*GCOLS;
  float gp=0.f, dn=0.f;
  #pragma unroll
  for (int s=0;s<4;s++){ gp += b2f(G[base+co+c+s*SL]); dn += b2f(G[base+dcol+s*SL]); }
  gp /= (dn + 1e-16f);
  float v = gp*gp;
  #pragma unroll
  for (int o=32;o>0;o>>=1) v+=__shfl_down(v,o);
  if ((c&63)==0) sm[c>>6]=v;
  __syncthreads();
  if (c==0) tot = sm[0]+sm[1]+sm[2]+sm[3];
  __syncthreads();
  float nrm = sqrtf(tot);
  float x = gp/fmaxf(nrm,1e-12f);
  g[(size_t)n*HIDC+c]=1.f/(1.f+__expf(-x));
}

// ---------------- discriminator ----------------
__global__ void k_disc(const float* __restrict__ z, const float* __restrict__ za,
                       const float* __restrict__ V, const float* __restrict__ Va,
                       const float* __restrict__ bbp, const float* __restrict__ biasp,
                       float* __restrict__ ret, float* __restrict__ ret_a){
  __shared__ float sm[16];
  int n=blockIdx.x, c=threadIdx.x;
  float ez = z[(size_t)n*HIDC+c], ea = za[(size_t)n*HIDC+c];
  float v  = V[(size_t)n*HIDC+c], va = Va[(size_t)n*HIDC+c];
  float p1=ez*v, p2=ea*v, p3=ea*va, p4=ez*va;
  #pragma unroll
  for (int o=32;o>0;o>>=1){
    p1+=__shfl_down(p1,o); p2+=__shfl_down(p2,o);
    p3+=__shfl_down(p3,o); p4+=__shfl_down(p4,o);
  }
  int lane=c&63, w=c>>6;
  if (lane==0){ sm[w]=p1; sm[4+w]=p2; sm[8+w]=p3; sm[12+w]=p4; }
  __syncthreads();
  if (c==0){
    float add = bbp[0]+biasp[0];
    ret[n*2+0]   = sm[0]+sm[1]+sm[2]+sm[3]   + add;
    ret[n*2+1]   = sm[4]+sm[5]+sm[6]+sm[7]   + add;
    ret_a[n*2+0] = sm[8]+sm[9]+sm[10]+sm[11] + add;
    ret_a[n*2+1] = sm[12]+sm[13]+sm[14]+sm[15] + add;
  }
}

extern "C" void kernel_launch(void* const* d_in, const int* in_sizes, int n_in,
                              void* d_out, int out_size, void* d_ws, size_t ws_size,
                              hipStream_t stream){
  (void)in_sizes; (void)n_in; (void)out_size; (void)ws_size;
  const float* feat   = (const float*)d_in[0];
  const float* feat_a = (const float*)d_in[1];
  const int*   ei     = (const int*)d_in[2];
  const float* ew     = (const float*)d_in[3];
  const int*   mask   = (const int*)d_in[4];
  const float* W1     = (const float*)d_in[5];
  const float* a_src1 = (const float*)d_in[6];
  const float* a_dst1 = (const float*)d_in[7];
  const float* b1     = (const float*)d_in[8];
  const float* W2     = (const float*)d_in[9];
  const float* a_src2 = (const float*)d_in[10];
  const float* a_dst2 = (const float*)d_in[11];
  const float* b2     = (const float*)d_in[12];
  const float* pw1    = (const float*)d_in[13];
  const float* pb1    = (const float*)d_in[14];
  const float* pw2    = (const float*)d_in[15];
  const float* pb2    = (const float*)d_in[16];
  const float* dw     = (const float*)d_in[17];
  const float* dbb    = (const float*)d_in[18];
  const float* dbias  = (const float*)d_in[19];

  float* out  = (float*)d_out;
  float* z    = out;
  float* hout = out + (size_t)N_NODES*HIDC;
  float* ret  = hout + (size_t)N_NODES*F_INF;
  float* ret_a= ret + (size_t)N_NODES*2;

  char* cur = (char*)d_ws;
  auto alloc = [&](size_t bytes)->void*{
    void* p = cur; cur += (bytes + 255) & ~(size_t)255; return p;
  };
  // SLB: time-shared — proj bf16 slabs (16.8MB) -> mask bf16 slabs (18.9MB)
  void* SLB = alloc((size_t)4*N_NODES*GCOLS*4);
  u16* W1T  = (u16*)alloc((size_t)HIDC*FPAD*2);
  u16* W2T  = (u16*)alloc((size_t)NPAD*HIDC*2);
  u16* pw1T = (u16*)alloc((size_t)POOLH*HIDC*2);
  u16* qT   = (u16*)alloc((size_t)GCOLS*N_NODES*2);
  u16* dwb  = (u16*)alloc((size_t)HIDC*HIDC*2);
  float* h1st = (float*)alloc((size_t)2*N_NODES*HIDC*4);
  float* za   = (float*)alloc((size_t)N_NODES*HIDC*4);
  float* agg  = (float*)alloc((size_t)N_NODES*HIDC*4);
  float* Vst  = (float*)alloc((size_t)2*N_NODES*HIDC*4); // Hp, then V;Va
  float* gv   = (float*)alloc((size_t)N_NODES*HIDC*4);
  float* gva  = (float*)alloc((size_t)N_NODES*HIDC*4);
  float* ss1 = (float*)alloc((size_t)2*N_NODES*4*4);
  float* sd1 = (float*)alloc((size_t)2*N_NODES*4*4);
  float* ssz = (float*)alloc(N_NODES*4);
  float* sdz = (float*)alloc(N_NODES*4);
  float* wsrc= (float*)alloc(HIDC*4);
  float* wdst= (float*)alloc(HIDC*4);
  float* scAB = (float*)alloc((size_t)2*N_NODES*4);
  float* pvA = (float*)alloc(N_NODES*4);
  float* pvB = (float*)alloc(N_NODES*4);
  float* Mb  = (float*)alloc(256);
  int* deg    = (int*)alloc(N_NODES*4);
  int* off    = (int*)alloc((N_NODES+64)*4);
  int* cursor = (int*)alloc(N_NODES*4);
  int* csrc   = (int*)alloc(NEDGE*4);
  float* csw  = (float*)alloc(NEDGE*4);

  float* V   = Vst;
  float* Va  = Vst + (size_t)N_NODES*HIDC;

  // ---- CSR build + independent small prep ----
  hipMemsetAsync(deg, 0, N_NODES*sizeof(int), stream);
  hipMemsetAsync(cursor, 0, N_NODES*sizeof(int), stream);
  hipMemsetAsync(qT + (size_t)514*N_NODES, 0, (size_t)(GCOLS-514)*N_NODES*2, stream);
  k_deg<<<NEDGE/256,256,0,stream>>>(ei+NEDGE, deg);
  k_scan<<<1,1024,0,stream>>>(deg, off);
  k_fill<<<NEDGE/256,256,0,stream>>>(ei, ew, off, cursor, csrc, csw);
  k_wvec<<<HIDC,256,0,stream>>>(W2, a_src2, a_dst2, wsrc, wdst);

  // ---- weight conversions ----
  k_trcvt<<<dim3(HIDC/32, FPAD/32),256,0,stream>>>(W1, W1T, F_INF, HIDC, FPAD, nullptr);
  k_trcvt<<<dim3(NPAD/32, HIDC/32),256,0,stream>>>(W2, W2T, HIDC, F_INF, HIDC, nullptr);
  k_trcvt<<<dim3(POOLH/32, HIDC/32),256,0,stream>>>(pw1, pw1T, HIDC, POOLH, HIDC, nullptr);
  k_cvt<<<HIDC*HIDC/4/256,256,0,stream>>>(dw, dwb, HIDC, HIDC, HIDC);

  // ---- stacked projection: BM=128, full-N, split-K=4, bf16 slabs ----
  // (round-15 proven config: 256 blocks, 128KB LDS)
  k_mg<0,128,256,2,4,1><<<dim3(2*N_NODES/128, 1, 4),512,0,stream>>>(
      feat, feat_a, N_NODES, W1T, SLB, nullptr,
      2*N_NODES, HIDC, FPAD, F_INF, F_INF, FPAD, HIDC, 768);
  k_hred<<<2*N_NODES,256,0,stream>>>((const u16*)SLB, h1st, a_src1, a_dst1, ss1, sd1);

  // ---- GAT1 both branches + fused GAT2 scores ----
  k_gat1<<<2*N_NODES,256,0,stream>>>(h1st, ss1, sd1, off, csrc, csw, b1, z, za,
                                     wsrc, wdst, ssz, sdz);

  // ---- GAT2: aggregate z, then hout = agg @ W2 + b2 ----
  // hout GEMM: BM=128, BN=128 -> staged 144MB (was 284), 768 blocks = 3 waves.
  k_gatz<<<N_NODES,256,0,stream>>>(z, ssz, sdz, off, csrc, csw, agg);
  k_mg<0,128,128,2,4,0><<<dim3(N_NODES/128, NPAD/128, 1),512,0,stream>>>(
      agg, agg, N_NODES, W2T, hout, b2,
      N_NODES, F_INF, HIDC, HIDC, HIDC, HIDC, F_INF, HIDC);

  // ---- pooling MLP as GEMM: Hp = [z;za] @ pw1 ----
  k_mg<0,64,64,2,2,0><<<dim3(2*N_NODES/64, POOLH/64, 1),256,0,stream>>>(
      z, za, N_NODES, pw1T, Vst, nullptr,
      2*N_NODES, POOLH, HIDC, HIDC, HIDC, HIDC, POOLH, HIDC);
  k_score<<<2*N_NODES/4,256,0,stream>>>(Vst, pb1, pw2, pb2, scAB);
  k_maxred2<<<2,1024,0,stream>>>(scAB, Mb);
  k_p2<<<N_NODES/256,256,0,stream>>>(scAB, Mb, pvA, pvB, qT);
  k_trcvt<<<dim3(HIDC/32, N_NODES/32),256,0,stream>>>(z,  qT, N_NODES, HIDC, N_NODES, pvA);
  k_trcvt<<<dim3(HIDC/32, N_NODES/32),256,0,stream>>>(za, qT + (size_t)HIDC*N_NODES, N_NODES, HIDC, N_NODES, pvB);

  // ---- masked-softmax GEMM: G = Mask @ [q | qa | pA | pB] ----
  // round-15 proven config: BM=64 BN=192, 2x4 waves, split-K=4, bf16 slabs.
  k_mg<1,64,192,2,4,1><<<dim3(N_NODES/64, GCOLS/192, 4),512,0,stream>>>(
      mask, mask, 2*N_NODES, qT, SLB, nullptr,
      N_NODES, GCOLS, N_NODES, N_NODES, N_NODES, N_NODES, GCOLS, 1024);
  k_gfin<<<dim3(N_NODES,2),256,0,stream>>>((const u16*)SLB, gv, gva);

  // ---- discriminator: [V;Va] = [gv;gva] @ dw^T ----
  k_mg<0,64,64,2,2,0><<<dim3(2*N_NODES/64, HIDC/64, 1),256,0,stream>>>(
      gv, gva, N_NODES, dwb, Vst, nullptr,
      2*N_NODES, HIDC, HIDC, HIDC, HIDC, HIDC, HIDC, HIDC);
  k_disc<<<N_NODES,256,0,stream>>>(z, za, V, Va, dbb, dbias, ret, ret_a);
}